// Round 20
// baseline (871.239 us; speedup 1.0000x reference)
//
#include <hip/hip_runtime.h>

typedef float f32x4 __attribute__((ext_vector_type(4)));
typedef long lx2 __attribute__((ext_vector_type(2)));

__device__ __forceinline__ float h2f(unsigned short h) {
  return (float)__builtin_bit_cast(_Float16, h);
}
__device__ __forceinline__ unsigned short f2h(float f) {
  return __builtin_bit_cast(unsigned short, (_Float16)f);
}

#if __has_builtin(__builtin_amdgcn_cvt_pk_fp8_f32)
#define HW_FP8 1
#else
#define HW_FP8 0
#endif

// fp32 -> OCP e4m3fn (software fallback): RNE, saturating, subnormal-correct
__device__ __forceinline__ unsigned char f2e4_sw(float f) {
  unsigned short h = __builtin_bit_cast(unsigned short, (_Float16)f);
  unsigned s = (h >> 8) & 0x80u;
  unsigned ae = h & 0x7FFFu;
  if (ae >= 0x5F00u) return (unsigned char)(s | 0x7Eu);
  if (ae >= 0x2400u) {
    unsigned t = ae - 0x2000u;
    t = (t + 0x3Fu + ((t >> 7) & 1u)) >> 7;
    return (unsigned char)(s | t);
  }
  float v = (float)__builtin_bit_cast(_Float16, (unsigned short)ae) * 512.0f;
  int n = (int)rintf(v);
  return (unsigned char)(s | (unsigned)n);
}

__device__ __forceinline__ unsigned pk4e4(float a, float b, float c, float d) {
#if HW_FP8
  int lo = __builtin_amdgcn_cvt_pk_fp8_f32(a, b, 0, false);
  return (unsigned)__builtin_amdgcn_cvt_pk_fp8_f32(c, d, lo, true);
#else
  return (unsigned)f2e4_sw(a) | ((unsigned)f2e4_sw(b) << 8) |
         ((unsigned)f2e4_sw(c) << 16) | ((unsigned)f2e4_sw(d) << 24);
#endif
}
__device__ __forceinline__ unsigned pk2e4(float a, float b) {
#if HW_FP8
  return (unsigned)__builtin_amdgcn_cvt_pk_fp8_f32(a, b, 0, false) & 0xFFFFu;
#else
  return (unsigned)f2e4_sw(a) | ((unsigned)f2e4_sw(b) << 8);
#endif
}

__device__ __forceinline__ void gload_lds16(const void* g, void* l) {
  __builtin_amdgcn_global_load_lds(
      (const __attribute__((address_space(1))) void*)g,
      (__attribute__((address_space(3))) void*)l, 16, 0, 0);
}

// ---------------------------------------------------------------------------
// fp32 -> fp8 streaming convert, 3 inputs (blockIdx.y selects), 8 elems/thread
// ---------------------------------------------------------------------------
__global__ __launch_bounds__(256) void conv3(
    const float* __restrict__ A0, const float* __restrict__ A1,
    const float* __restrict__ A2, unsigned char* __restrict__ X0,
    unsigned char* __restrict__ X1, unsigned char* __restrict__ X2)
{
  const int z = blockIdx.y;
  const float* in = (z == 0) ? A0 : (z == 1) ? A1 : A2;
  unsigned char* out = (z == 0) ? X0 : (z == 1) ? X1 : X2;
  const size_t i = (size_t)blockIdx.x * 256 + threadIdx.x;   // 8-elem groups
  const float4 a = ((const float4*)in)[i * 2];
  const float4 b = ((const float4*)in)[i * 2 + 1];
  uint2 o;
  o.x = pk4e4(a.x, a.y, a.z, a.w);
  o.y = pk4e4(b.x, b.y, b.z, b.w);
  ((uint2*)out)[i] = o;
}

// ---------------------------------------------------------------------------
// MERGED fp8 projection kernel: grid 1536 = 3 x 512; z selects {q,k,v}.
// A = X8 (fp8 input, pre-converted); B = WT8 (fp8, x8). Pure gload_lds
// staging, BK=128, 8 iterations. 3 blocks/CU (launch_bounds 512,6;
// VGPR 60, LDS 48KB x3 = 144KB <= 160KB) for cross-block stall overlap.
// acc = 8*(x@W); e = exp(0.125*acc + bias).
// z==0: Eq8 = f8(e/16) [row][col] + fused row-sums (raw e).
// z>0 : ET8 = f8(e/16) TRANSPOSED [col][row] packed 4B + fused col-sums.
// ---------------------------------------------------------------------------
__global__ __launch_bounds__(512, 6) void proj3(
    const unsigned char* __restrict__ X0, const unsigned char* __restrict__ X1,
    const unsigned char* __restrict__ X2, const unsigned char* __restrict__ WT8b,
    const float* __restrict__ b0, const float* __restrict__ b1,
    const float* __restrict__ b2, unsigned char* __restrict__ C0,
    unsigned char* __restrict__ C1, unsigned char* __restrict__ C2,
    float* __restrict__ s0, float* __restrict__ s1, float* __restrict__ s2)
{
  __shared__ alignas(16) unsigned char smem[49152];  // A 16KB | B 32KB
  const int tid  = threadIdx.x;
  const int lane = tid & 63;
  const int wave = tid >> 6;
  const int waveM = wave >> 2;
  const int waveN = wave & 3;

  // bijective XCD swizzle over 1536 blocks (cpx = 192)
  const int wg = (int)blockIdx.x;
  const int w  = (wg & 7) * 192 + (wg >> 3);
  const int z  = w / 512;
  const int wl = w - z * 512;
  const int x  = wl & 3;
  const int rem = wl >> 2;
  const int y  = rem & 31;
  const int bz = rem >> 5;

  const unsigned char* Xf = (z == 0) ? X0 : (z == 1) ? X1 : X2;
  const float* bi = (z == 0) ? b0 : (z == 1) ? b1 : b2;
  unsigned char* Cp = (z == 0) ? C0 : (z == 1) ? C1 : C2;
  float* sums = (z == 0) ? s0 : (z == 1) ? s1 : s2;

  const int m0 = y * 128, n0 = x * 256;

  // staging: LDS dst linear tid*16 (+8192); src inverse-swizzled (byte units)
  const int srow = tid >> 3;                               // 0..63
  const int scol = ((tid * 16) & 127) ^ ((srow & 7) << 4);
  const unsigned char* BpR = WT8b + ((size_t)z << 20)
                             + (size_t)(n0 + srow) * 1024 + scol;
  const unsigned char* ApR = Xf + (size_t)bz * (4096L * 1024)
                             + (size_t)(m0 + srow) * 1024 + scol;
  const unsigned oA0 = (unsigned)tid * 16;

  // fragment byte offsets (kk=0); kk=1 is ^64 (swizzle field bits 4-6)
  int offA[4], offB[4];
  {
    const int q16 = (lane >> 4) << 4;
#pragma unroll
    for (int mi = 0; mi < 4; ++mi) {
      const int r = waveM * 64 + mi * 16 + (lane & 15);
      offA[mi] = r * 128 + (q16 ^ ((r & 7) << 4));
    }
#pragma unroll
    for (int ni = 0; ni < 4; ++ni) {
      const int r = waveN * 64 + ni * 16 + (lane & 15);
      offB[ni] = 16384 + r * 128 + (q16 ^ ((r & 7) << 4));
    }
  }

  f32x4 acc[4][4] = {};

  for (int kt = 0; kt < 8; ++kt) {
    const size_t kb = (size_t)kt * 128;
    gload_lds16(ApR + kb,              smem + oA0);
    gload_lds16(ApR + 64 * 1024 + kb,  smem + oA0 + 8192);
    gload_lds16(BpR + kb,              smem + 16384 + oA0);
    gload_lds16(BpR + 64 * 1024 + kb,  smem + 16384 + oA0 + 8192);
    gload_lds16(BpR + 128 * 1024 + kb, smem + 16384 + oA0 + 16384);
    gload_lds16(BpR + 192 * 1024 + kb, smem + 16384 + oA0 + 24576);
    __syncthreads();
#pragma unroll
    for (int kk = 0; kk < 2; ++kk) {
      const int kx = kk << 6;
      lx2 aF[4], bF[4];
#pragma unroll
      for (int mi = 0; mi < 4; ++mi) aF[mi] = *(const lx2*)&smem[offA[mi] ^ kx];
#pragma unroll
      for (int ni = 0; ni < 4; ++ni) bF[ni] = *(const lx2*)&smem[offB[ni] ^ kx];
#pragma unroll
      for (int h = 0; h < 2; ++h)
#pragma unroll
        for (int mi = 0; mi < 4; ++mi)
#pragma unroll
          for (int ni = 0; ni < 4; ++ni)
            acc[mi][ni] = __builtin_amdgcn_mfma_f32_16x16x32_fp8_fp8(
                aF[mi][h], bF[ni][h], acc[mi][ni], 0, 0, 0);
    }
    __syncthreads();
  }

  // ---- epilogue (acc = 8*x@W -> e = exp(0.125*acc + bias)) ----
  const int rb = (lane >> 4) * 4;
  const int cb_ = lane & 15;
  const long sC = 4096L * 1024;

  if (z == 0) {
#pragma unroll
    for (int m = 0; m < 4; ++m) {
      const int row0 = m0 + waveM * 64 + m * 16 + rb;
      float rs0 = 0, rs1 = 0, rs2 = 0, rs3 = 0;
#pragma unroll
      for (int n = 0; n < 4; ++n) {
        const int col = n0 + waveN * 64 + n * 16 + cb_;
        const float badd = bi[col];
        const float e0 = __expf(acc[m][n][0] * 0.125f + badd);
        const float e1 = __expf(acc[m][n][1] * 0.125f + badd);
        const float e2 = __expf(acc[m][n][2] * 0.125f + badd);
        const float e3 = __expf(acc[m][n][3] * 0.125f + badd);
        const unsigned p01 = pk2e4(e0 * 0.0625f, e1 * 0.0625f);
        const unsigned p23 = pk2e4(e2 * 0.0625f, e3 * 0.0625f);
        unsigned char* C8 = Cp + (long)bz * sC;
        C8[(size_t)(row0 + 0) * 1024 + col] = (unsigned char)(p01 & 0xff);
        C8[(size_t)(row0 + 1) * 1024 + col] = (unsigned char)((p01 >> 8) & 0xff);
        C8[(size_t)(row0 + 2) * 1024 + col] = (unsigned char)(p23 & 0xff);
        C8[(size_t)(row0 + 3) * 1024 + col] = (unsigned char)((p23 >> 8) & 0xff);
        rs0 += e0; rs1 += e1; rs2 += e2; rs3 += e3;
      }
#pragma unroll
      for (int off = 1; off <= 8; off <<= 1) {
        rs0 += __shfl_xor(rs0, off);
        rs1 += __shfl_xor(rs1, off);
        rs2 += __shfl_xor(rs2, off);
        rs3 += __shfl_xor(rs3, off);
      }
      if ((lane & 15) == 0) {
        float* s = sums + (size_t)bz * 4096 + row0;
        atomicAdd(s + 0, rs0);
        atomicAdd(s + 1, rs1);
        atomicAdd(s + 2, rs2);
        atomicAdd(s + 3, rs3);
      }
    }
  } else {
    float cs[4] = {0.f, 0.f, 0.f, 0.f};
#pragma unroll
    for (int m = 0; m < 4; ++m) {
      const int row0 = m0 + waveM * 64 + m * 16 + rb;
#pragma unroll
      for (int n = 0; n < 4; ++n) {
        const int col = n0 + waveN * 64 + n * 16 + cb_;
        const float badd = bi[col];
        float ev[4];
        float ls = 0.f;
#pragma unroll
        for (int r = 0; r < 4; ++r) {
          ev[r] = __expf(acc[m][n][r] * 0.125f + badd);
          ls += ev[r];
        }
        cs[n] += ls;
        *(unsigned*)(Cp + (long)bz * sC + ((size_t)col << 12) + row0) =
            pk4e4(ev[0] * 0.0625f, ev[1] * 0.0625f, ev[2] * 0.0625f, ev[3] * 0.0625f);
      }
    }
#pragma unroll
    for (int n = 0; n < 4; ++n) {
      cs[n] += __shfl_xor(cs[n], 16);
      cs[n] += __shfl_xor(cs[n], 32);
    }
    if (lane < 16) {
#pragma unroll
      for (int n = 0; n < 4; ++n) {
        const int col = n0 + waveN * 64 + n * 16 + lane;
        atomicAdd(sums + ((size_t)bz << 10) + col, cs[n]);
      }
    }
  }
}

// ---------------------------------------------------------------------------
// fp8 GEMM, 128x256 tile, C = A @ Bt^T (e4m3 operands, BK=128, fp32 acc).
// K is PER-SLICE k-length; ldk is the row stride. 3 blocks/CU.
// OUTMODE 2: fp16 split-K partial (slice zt)
//         5: fp32 acc/(256*sums[row]) + bias[col]
// ---------------------------------------------------------------------------
template <int OUTMODE>
__global__ __launch_bounds__(512, 6) void gemm8(
    const unsigned char* __restrict__ A, const unsigned char* __restrict__ Bt,
    void* __restrict__ Cv, const float* __restrict__ bias,
    const float* __restrict__ sums,
    int N, int K, int ldk, int gx, int gy, int nsplit,
    long sA, long sB, long sC)
{
  __shared__ alignas(16) unsigned char smem[49152];
  const int tid  = threadIdx.x;
  const int lane = tid & 63;
  const int wave = tid >> 6;
  const int waveM = wave >> 2;
  const int waveN = wave & 3;

  const int nwg = (int)gridDim.x;
  const int cpx = nwg >> 3;
  const int wg  = (int)blockIdx.x;
  const int w   = (wg & 7) * cpx + (wg >> 3);
  const int x   = w % gx;
  const int rem = w / gx;
  const int y   = rem % gy;
  const int zt  = rem / gy;
  const int bz  = zt / nsplit;
  const int sp  = zt % nsplit;

  const int m0 = y * 128, n0 = x * 256;
  const size_t ldkB = (size_t)ldk;
  const size_t ldkB64 = ldkB * 64, ldkB128 = ldkB * 128;

  const int srow = tid >> 3;
  const int scol = ((tid * 16) & 127) ^ ((srow & 7) << 4);
  const char* ApR;
  const char* BpR;
  {
    const char* Ab = (const char*)A + (long)bz * sA + (long)sp * K + (size_t)m0 * ldkB;
    const char* Bb = (const char*)Bt + (long)bz * sB + (long)sp * K + (size_t)n0 * ldkB;
    ApR = Ab + (size_t)srow * ldkB + scol;
    BpR = Bb + (size_t)srow * ldkB + scol;
  }
  const unsigned oA0 = (unsigned)tid * 16;

  int offA[4], offB[4];
  {
    const int q16 = (lane >> 4) << 4;
#pragma unroll
    for (int mi = 0; mi < 4; ++mi) {
      const int r = waveM * 64 + mi * 16 + (lane & 15);
      offA[mi] = r * 128 + (q16 ^ ((r & 7) << 4));
    }
#pragma unroll
    for (int ni = 0; ni < 4; ++ni) {
      const int r = waveN * 64 + ni * 16 + (lane & 15);
      offB[ni] = 16384 + r * 128 + (q16 ^ ((r & 7) << 4));
    }
  }

  f32x4 acc[4][4] = {};

  const int nk = K >> 7;
  for (int kt = 0; kt < nk; ++kt) {
    const size_t kb = (size_t)kt * 128;
    gload_lds16(ApR + kb,                     smem + oA0);
    gload_lds16(ApR + ldkB64 + kb,            smem + oA0 + 8192);
    gload_lds16(BpR + kb,                     smem + 16384 + oA0);
    gload_lds16(BpR + ldkB64 + kb,            smem + 16384 + oA0 + 8192);
    gload_lds16(BpR + ldkB128 + kb,           smem + 16384 + oA0 + 16384);
    gload_lds16(BpR + ldkB128 + ldkB64 + kb,  smem + 16384 + oA0 + 24576);
    __syncthreads();
#pragma unroll
    for (int kk = 0; kk < 2; ++kk) {
      const int kx = kk << 6;
      lx2 aF[4], bF[4];
#pragma unroll
      for (int mi = 0; mi < 4; ++mi) aF[mi] = *(const lx2*)&smem[offA[mi] ^ kx];
#pragma unroll
      for (int ni = 0; ni < 4; ++ni) bF[ni] = *(const lx2*)&smem[offB[ni] ^ kx];
#pragma unroll
      for (int h = 0; h < 2; ++h)
#pragma unroll
        for (int mi = 0; mi < 4; ++mi)
#pragma unroll
          for (int ni = 0; ni < 4; ++ni)
            acc[mi][ni] = __builtin_amdgcn_mfma_f32_16x16x32_fp8_fp8(
                aF[mi][h], bF[ni][h], acc[mi][ni], 0, 0, 0);
    }
    __syncthreads();
  }

  const int rb = (lane >> 4) * 4;
  const int cb_ = lane & 15;
  const long zout = (OUTMODE == 2) ? (long)zt : (long)bz;
#pragma unroll
  for (int m = 0; m < 4; ++m) {
    const int row0 = m0 + waveM * 64 + m * 16 + rb;
    float i0 = 0, i1 = 0, i2 = 0, i3 = 0;
    if (OUTMODE == 5) {
      const float4 s4 = *(const float4*)&sums[(size_t)zout * 4096 + row0];
      i0 = 1.0f / (256.0f * s4.x); i1 = 1.0f / (256.0f * s4.y);
      i2 = 1.0f / (256.0f * s4.z); i3 = 1.0f / (256.0f * s4.w);
    }
#pragma unroll
    for (int n = 0; n < 4; ++n) {
      const int col = n0 + waveN * 64 + n * 16 + cb_;
      if (OUTMODE == 2) {
#pragma unroll
        for (int r = 0; r < 4; ++r)
          ((unsigned short*)Cv)[zout * sC + (size_t)(row0 + r) * N + col] = f2h(acc[m][n][r]);
      } else {
        const float badd = bias[col];
        float* C32 = (float*)Cv;
        C32[zout * sC + (size_t)(row0 + 0) * N + col] = acc[m][n][0] * i0 + badd;
        C32[zout * sC + (size_t)(row0 + 1) * N + col] = acc[m][n][1] * i1 + badd;
        C32[zout * sC + (size_t)(row0 + 2) * N + col] = acc[m][n][2] * i2 + badd;
        C32[zout * sC + (size_t)(row0 + 3) * N + col] = acc[m][n][3] * i3 + badd;
      }
    }
  }
}

// ---------------------------------------------------------------------------
// Weight transpose -> fp8 x8 (4 weights, z selects): WT8[z][c][r] = f8(8*W[r][c])
// ---------------------------------------------------------------------------
__global__ __launch_bounds__(256) void w_tr8(
    const float* __restrict__ W0, const float* __restrict__ W1,
    const float* __restrict__ W2, const float* __restrict__ W3,
    unsigned char* __restrict__ WT8b)
{
  __shared__ float tile[64][65];
  const int z = blockIdx.z;
  const float* W = (z == 0) ? W0 : (z == 1) ? W1 : (z == 2) ? W2 : W3;
  unsigned char* WT8 = WT8b + ((size_t)z << 20);
  const int c0 = blockIdx.x * 64;
  const int r0 = blockIdx.y * 64;
  const int tid = threadIdx.x;
  const int r = tid >> 2;
  const int cq = (tid & 3) * 16;
#pragma unroll
  for (int i = 0; i < 4; ++i) {
    const int c = cq + i * 4;
    const float4 v = *(const float4*)&W[(size_t)(r0 + r) * 1024 + c0 + c];
    tile[r][c + 0] = v.x;
    tile[r][c + 1] = v.y;
    tile[r][c + 2] = v.z;
    tile[r][c + 3] = v.w;
  }
  __syncthreads();
  const int c = tid >> 2;
  const int rq = (tid & 3) * 16;
  unsigned u4[4];
#pragma unroll
  for (int j = 0; j < 4; ++j)
    u4[j] = pk4e4(tile[rq + 4 * j + 0][c] * 8.f, tile[rq + 4 * j + 1][c] * 8.f,
                  tile[rq + 4 * j + 2][c] * 8.f, tile[rq + 4 * j + 3][c] * 8.f);
  *(uint4*)(WT8 + (size_t)(c0 + c) * 1024 + r0 + rq) = *(const uint4*)u4;
}

// ---------------------------------------------------------------------------
// split-K x4 reduce of fp16 partials -> fp8 M with normalization:
// M8[b][dk][dv] = f8( sum * 2^22 / (skr[b][dk] * svr[b][dv]) )
// ---------------------------------------------------------------------------
__global__ __launch_bounds__(256) void red4m(
    const unsigned short* __restrict__ P, const float* __restrict__ skr,
    const float* __restrict__ svr, unsigned char* __restrict__ O)
{
  const int i = blockIdx.x * 256 + threadIdx.x;
  const int b = i >> 18;
  const int j = i & 262143;
  const int dk = j >> 8;
  const int dv0 = (j & 255) << 2;
  float s0 = 0, s1 = 0, s2 = 0, s3 = 0;
#pragma unroll
  for (int sl = 0; sl < 4; ++sl) {
    const uint2 u = *(const uint2*)(P + (((long)(b * 4 + sl)) << 20) + ((long)j << 2));
    s0 += h2f(u.x & 0xffff); s1 += h2f(u.x >> 16);
    s2 += h2f(u.y & 0xffff); s3 += h2f(u.y >> 16);
  }
  const float fk = 4194304.0f / skr[(b << 10) + dk];
  const float4 fv = *(const float4*)&svr[(b << 10) + dv0];
  ((unsigned*)O)[i] = pk4e4(s0 * fk / fv.x, s1 * fk / fv.y,
                            s2 * fk / fv.z, s3 * fk / fv.w);
}

// ---------------------------------------------------------------------------
// split-K x4 reduce -> fp8 GT: GT8[b][i] = f8( sum / 32 )
// ---------------------------------------------------------------------------
__global__ __launch_bounds__(256) void red4g(
    const unsigned short* __restrict__ P, unsigned char* __restrict__ O)
{
  const int i = blockIdx.x * 256 + threadIdx.x;
  const int b = i >> 18;
  const int j = i & 262143;
  float s0 = 0, s1 = 0, s2 = 0, s3 = 0;
#pragma unroll
  for (int sl = 0; sl < 4; ++sl) {
    const uint2 u = *(const uint2*)(P + (((long)(b * 4 + sl)) << 20) + ((long)j << 2));
    s0 += h2f(u.x & 0xffff); s1 += h2f(u.x >> 16);
    s2 += h2f(u.y & 0xffff); s3 += h2f(u.y >> 16);
  }
  ((unsigned*)O)[i] = pk4e4(s0 * 0.03125f, s1 * 0.03125f,
                            s2 * 0.03125f, s3 * 0.03125f);
}

// ---------------------------------------------------------------------------
extern "C" void kernel_launch(void* const* d_in, const int* in_sizes, int n_in,
                              void* d_out, int out_size, void* d_ws, size_t ws_size,
                              hipStream_t stream) {
  const float* q  = (const float*)d_in[0];
  const float* k  = (const float*)d_in[1];
  const float* v  = (const float*)d_in[2];
  const float* Wq = (const float*)d_in[3];
  const float* bq = (const float*)d_in[4];
  const float* Wk = (const float*)d_in[5];
  const float* bk = (const float*)d_in[6];
  const float* Wv = (const float*)d_in[7];
  const float* bv = (const float*)d_in[8];
  const float* Wo = (const float*)d_in[9];
  const float* bo = (const float*)d_in[10];
  float* out = (float*)d_out;

  // workspace (~143 MB)
  char* p = (char*)d_ws;
  unsigned short* Part = (unsigned short*)p; p += 33554432;   // fp16 [16][2^20]
  unsigned char* WT8b = (unsigned char*)p;   p += 4194304;    // 4x fp8 [1024][1024], x8
  unsigned char* Xq8  = (unsigned char*)p;   p += 16777216;   // fp8 [4][4096][1024]
  unsigned char* Xk8  = (unsigned char*)p;   p += 16777216;
  unsigned char* Xv8  = (unsigned char*)p;   p += 16777216;
  unsigned char* Eq8  = (unsigned char*)p;   p += 16777216;   // fp8 [4][4096][1024]
  unsigned char* ETk8 = (unsigned char*)p;   p += 16777216;   // fp8 [4][1024][4096]
  unsigned char* ETv8 = (unsigned char*)p;   p += 16777216;
  unsigned char* Mh8  = (unsigned char*)p;   p += 4194304;    // fp8 [4][1024][1024]
  unsigned char* GT8  = (unsigned char*)p;   p += 4194304;    // fp8 [4][1024][1024]
  float* sqraw = (float*)p; p += 16384 * 4;   // raw row-sums of Eq
  float* skraw = (float*)p; p += 4096 * 4;    // raw col-sums of Ek
  float* svraw = (float*)p; p += 4096 * 4;    // raw col-sums of Ev

  const dim3 blk(256);
  const dim3 blk512(512);
  const long S22 = 4096L * 1024;
  const long S20 = 1024L * 1024;

  // zero the atomic sum accumulators (96 KB; graph-capturable)
  hipMemsetAsync(sqraw, 0, (16384 + 4096 + 4096) * sizeof(float), stream);

  // weights -> fp8 x8 transposed (one launch)
  w_tr8<<<dim3(16, 16, 4), blk, 0, stream>>>(Wq, Wk, Wv, Wo, WT8b);

  // q,k,v fp32 -> fp8 (streaming; 192 MB read + 48 MB write)
  conv3<<<dim3(8192, 3), blk, 0, stream>>>(q, k, v, Xq8, Xk8, Xv8);

  // ---- merged fp8 projections (pure gload_lds core): Eq8/ETk8/ETv8 + sums
  proj3<<<1536, blk512, 0, stream>>>(Xq8, Xk8, Xv8, WT8b, bq, bk, bv,
                                     Eq8, ETk8, ETv8, sqraw, skraw, svraw);

  // ---- M partials (fp8 GEMM, K=4096 split x4, per-slice K=1024):
  //      Mh8 = f8(red4(P) * 2^22 / (sk*sv))  (= M_true * 2^14)
  gemm8<2><<<512, blk512, 0, stream>>>(ETk8, ETv8, Part, nullptr, nullptr,
      1024, 1024, 4096, 4, 8, 4, S22, S22, S20);
  red4m<<<4096, blk, 0, stream>>>(Part, skraw, svraw, Mh8);

  // ---- GTraw (fp8 GEMM, K=1024 split x4, per-slice K=256):
  //      GT8 = f8(red4(P)/32)  (= G^T * 2^12)
  gemm8<2><<<512, blk512, 0, stream>>>(WT8b + (3L << 20), Mh8, Part, nullptr, nullptr,
      1024, 256, 1024, 4, 8, 4, 0, S20, S20);
  red4g<<<4096, blk, 0, stream>>>(Part, GT8);

  // ---- Out (fp8 GEMM): Out = (Eq8 @ GT8^T)/(256*sq) + bo
  gemm8<5><<<512, blk512, 0, stream>>>(Eq8, GT8, out, bo, sqraw,
      1024, 1024, 1024, 4, 32, 1, S22, S20, S22);

  (void)in_sizes; (void)n_in; (void)out_size; (void)ws_size;
}

// Round 21
// 229.183 us; speedup vs baseline: 3.8015x; 3.8015x over previous
//
#include <hip/hip_runtime.h>

typedef float f32x4 __attribute__((ext_vector_type(4)));
typedef long lx2 __attribute__((ext_vector_type(2)));

__device__ __forceinline__ float h2f(unsigned short h) {
  return (float)__builtin_bit_cast(_Float16, h);
}
__device__ __forceinline__ unsigned short f2h(float f) {
  return __builtin_bit_cast(unsigned short, (_Float16)f);
}

#if __has_builtin(__builtin_amdgcn_cvt_pk_fp8_f32)
#define HW_FP8 1
#else
#define HW_FP8 0
#endif

// fp32 -> OCP e4m3fn (software fallback): RNE, saturating, subnormal-correct
__device__ __forceinline__ unsigned char f2e4_sw(float f) {
  unsigned short h = __builtin_bit_cast(unsigned short, (_Float16)f);
  unsigned s = (h >> 8) & 0x80u;
  unsigned ae = h & 0x7FFFu;
  if (ae >= 0x5F00u) return (unsigned char)(s | 0x7Eu);
  if (ae >= 0x2400u) {
    unsigned t = ae - 0x2000u;
    t = (t + 0x3Fu + ((t >> 7) & 1u)) >> 7;
    return (unsigned char)(s | t);
  }
  float v = (float)__builtin_bit_cast(_Float16, (unsigned short)ae) * 512.0f;
  int n = (int)rintf(v);
  return (unsigned char)(s | (unsigned)n);
}

__device__ __forceinline__ unsigned pk4e4(float a, float b, float c, float d) {
#if HW_FP8
  int lo = __builtin_amdgcn_cvt_pk_fp8_f32(a, b, 0, false);
  return (unsigned)__builtin_amdgcn_cvt_pk_fp8_f32(c, d, lo, true);
#else
  return (unsigned)f2e4_sw(a) | ((unsigned)f2e4_sw(b) << 8) |
         ((unsigned)f2e4_sw(c) << 16) | ((unsigned)f2e4_sw(d) << 24);
#endif
}
__device__ __forceinline__ unsigned pk2e4(float a, float b) {
#if HW_FP8
  return (unsigned)__builtin_amdgcn_cvt_pk_fp8_f32(a, b, 0, false) & 0xFFFFu;
#else
  return (unsigned)f2e4_sw(a) | ((unsigned)f2e4_sw(b) << 8);
#endif
}

__device__ __forceinline__ void gload_lds16(const void* g, void* l) {
  __builtin_amdgcn_global_load_lds(
      (const __attribute__((address_space(1))) void*)g,
      (__attribute__((address_space(3))) void*)l, 16, 0, 0);
}

// ---------------------------------------------------------------------------
// fp32 -> fp8 streaming convert, 3 inputs (blockIdx.y selects), 8 elems/thread
// ---------------------------------------------------------------------------
__global__ __launch_bounds__(256) void conv3(
    const float* __restrict__ A0, const float* __restrict__ A1,
    const float* __restrict__ A2, unsigned char* __restrict__ X0,
    unsigned char* __restrict__ X1, unsigned char* __restrict__ X2)
{
  const int z = blockIdx.y;
  const float* in = (z == 0) ? A0 : (z == 1) ? A1 : A2;
  unsigned char* out = (z == 0) ? X0 : (z == 1) ? X1 : X2;
  const size_t i = (size_t)blockIdx.x * 256 + threadIdx.x;   // 8-elem groups
  const float4 a = ((const float4*)in)[i * 2];
  const float4 b = ((const float4*)in)[i * 2 + 1];
  uint2 o;
  o.x = pk4e4(a.x, a.y, a.z, a.w);
  o.y = pk4e4(b.x, b.y, b.z, b.w);
  ((uint2*)out)[i] = o;
}

// ---------------------------------------------------------------------------
// MERGED fp8 projection kernel: grid 1536 = 3 x 512; z selects {q,k,v}.
// A = X8 (fp8 input, pre-converted); B = WT8 (fp8, x8). Pure gload_lds
// staging, BK=128, 8 iterations, 2 blocks/CU (launch_bounds 512,4 —
// (512,6) spilled the accumulators: VGPR 40 < 64 needed, FETCH 648MB, 4.8x
// slower; do NOT raise min-waves past what the acc footprint allows).
// acc = 8*(x@W); e = exp(0.125*acc + bias).
// z==0: Eq8 = f8(e/16) [row][col] + fused row-sums (raw e).
// z>0 : ET8 = f8(e/16) TRANSPOSED [col][row] packed 4B + fused col-sums.
// ---------------------------------------------------------------------------
__global__ __launch_bounds__(512, 4) void proj3(
    const unsigned char* __restrict__ X0, const unsigned char* __restrict__ X1,
    const unsigned char* __restrict__ X2, const unsigned char* __restrict__ WT8b,
    const float* __restrict__ b0, const float* __restrict__ b1,
    const float* __restrict__ b2, unsigned char* __restrict__ C0,
    unsigned char* __restrict__ C1, unsigned char* __restrict__ C2,
    float* __restrict__ s0, float* __restrict__ s1, float* __restrict__ s2)
{
  __shared__ alignas(16) unsigned char smem[49152];  // A 16KB | B 32KB
  const int tid  = threadIdx.x;
  const int lane = tid & 63;
  const int wave = tid >> 6;
  const int waveM = wave >> 2;
  const int waveN = wave & 3;

  // bijective XCD swizzle over 1536 blocks (cpx = 192)
  const int wg = (int)blockIdx.x;
  const int w  = (wg & 7) * 192 + (wg >> 3);
  const int z  = w / 512;
  const int wl = w - z * 512;
  const int x  = wl & 3;
  const int rem = wl >> 2;
  const int y  = rem & 31;
  const int bz = rem >> 5;

  const unsigned char* Xf = (z == 0) ? X0 : (z == 1) ? X1 : X2;
  const float* bi = (z == 0) ? b0 : (z == 1) ? b1 : b2;
  unsigned char* Cp = (z == 0) ? C0 : (z == 1) ? C1 : C2;
  float* sums = (z == 0) ? s0 : (z == 1) ? s1 : s2;

  const int m0 = y * 128, n0 = x * 256;

  // staging: LDS dst linear tid*16 (+8192); src inverse-swizzled (byte units)
  const int srow = tid >> 3;                               // 0..63
  const int scol = ((tid * 16) & 127) ^ ((srow & 7) << 4);
  const unsigned char* BpR = WT8b + ((size_t)z << 20)
                             + (size_t)(n0 + srow) * 1024 + scol;
  const unsigned char* ApR = Xf + (size_t)bz * (4096L * 1024)
                             + (size_t)(m0 + srow) * 1024 + scol;
  const unsigned oA0 = (unsigned)tid * 16;

  // fragment byte offsets (kk=0); kk=1 is ^64 (swizzle field bits 4-6)
  int offA[4], offB[4];
  {
    const int q16 = (lane >> 4) << 4;
#pragma unroll
    for (int mi = 0; mi < 4; ++mi) {
      const int r = waveM * 64 + mi * 16 + (lane & 15);
      offA[mi] = r * 128 + (q16 ^ ((r & 7) << 4));
    }
#pragma unroll
    for (int ni = 0; ni < 4; ++ni) {
      const int r = waveN * 64 + ni * 16 + (lane & 15);
      offB[ni] = 16384 + r * 128 + (q16 ^ ((r & 7) << 4));
    }
  }

  f32x4 acc[4][4] = {};

  for (int kt = 0; kt < 8; ++kt) {
    const size_t kb = (size_t)kt * 128;
    gload_lds16(ApR + kb,              smem + oA0);
    gload_lds16(ApR + 64 * 1024 + kb,  smem + oA0 + 8192);
    gload_lds16(BpR + kb,              smem + 16384 + oA0);
    gload_lds16(BpR + 64 * 1024 + kb,  smem + 16384 + oA0 + 8192);
    gload_lds16(BpR + 128 * 1024 + kb, smem + 16384 + oA0 + 16384);
    gload_lds16(BpR + 192 * 1024 + kb, smem + 16384 + oA0 + 24576);
    __syncthreads();
#pragma unroll
    for (int kk = 0; kk < 2; ++kk) {
      const int kx = kk << 6;
      lx2 aF[4], bF[4];
#pragma unroll
      for (int mi = 0; mi < 4; ++mi) aF[mi] = *(const lx2*)&smem[offA[mi] ^ kx];
#pragma unroll
      for (int ni = 0; ni < 4; ++ni) bF[ni] = *(const lx2*)&smem[offB[ni] ^ kx];
#pragma unroll
      for (int h = 0; h < 2; ++h)
#pragma unroll
        for (int mi = 0; mi < 4; ++mi)
#pragma unroll
          for (int ni = 0; ni < 4; ++ni)
            acc[mi][ni] = __builtin_amdgcn_mfma_f32_16x16x32_fp8_fp8(
                aF[mi][h], bF[ni][h], acc[mi][ni], 0, 0, 0);
    }
    __syncthreads();
  }

  // ---- epilogue (acc = 8*x@W -> e = exp(0.125*acc + bias)) ----
  const int rb = (lane >> 4) * 4;
  const int cb_ = lane & 15;
  const long sC = 4096L * 1024;

  if (z == 0) {
#pragma unroll
    for (int m = 0; m < 4; ++m) {
      const int row0 = m0 + waveM * 64 + m * 16 + rb;
      float rs0 = 0, rs1 = 0, rs2 = 0, rs3 = 0;
#pragma unroll
      for (int n = 0; n < 4; ++n) {
        const int col = n0 + waveN * 64 + n * 16 + cb_;
        const float badd = bi[col];
        const float e0 = __expf(acc[m][n][0] * 0.125f + badd);
        const float e1 = __expf(acc[m][n][1] * 0.125f + badd);
        const float e2 = __expf(acc[m][n][2] * 0.125f + badd);
        const float e3 = __expf(acc[m][n][3] * 0.125f + badd);
        const unsigned p01 = pk2e4(e0 * 0.0625f, e1 * 0.0625f);
        const unsigned p23 = pk2e4(e2 * 0.0625f, e3 * 0.0625f);
        unsigned char* C8 = Cp + (long)bz * sC;
        C8[(size_t)(row0 + 0) * 1024 + col] = (unsigned char)(p01 & 0xff);
        C8[(size_t)(row0 + 1) * 1024 + col] = (unsigned char)((p01 >> 8) & 0xff);
        C8[(size_t)(row0 + 2) * 1024 + col] = (unsigned char)(p23 & 0xff);
        C8[(size_t)(row0 + 3) * 1024 + col] = (unsigned char)((p23 >> 8) & 0xff);
        rs0 += e0; rs1 += e1; rs2 += e2; rs3 += e3;
      }
#pragma unroll
      for (int off = 1; off <= 8; off <<= 1) {
        rs0 += __shfl_xor(rs0, off);
        rs1 += __shfl_xor(rs1, off);
        rs2 += __shfl_xor(rs2, off);
        rs3 += __shfl_xor(rs3, off);
      }
      if ((lane & 15) == 0) {
        float* s = sums + (size_t)bz * 4096 + row0;
        atomicAdd(s + 0, rs0);
        atomicAdd(s + 1, rs1);
        atomicAdd(s + 2, rs2);
        atomicAdd(s + 3, rs3);
      }
    }
  } else {
    float cs[4] = {0.f, 0.f, 0.f, 0.f};
#pragma unroll
    for (int m = 0; m < 4; ++m) {
      const int row0 = m0 + waveM * 64 + m * 16 + rb;
#pragma unroll
      for (int n = 0; n < 4; ++n) {
        const int col = n0 + waveN * 64 + n * 16 + cb_;
        const float badd = bi[col];
        float ev[4];
        float ls = 0.f;
#pragma unroll
        for (int r = 0; r < 4; ++r) {
          ev[r] = __expf(acc[m][n][r] * 0.125f + badd);
          ls += ev[r];
        }
        cs[n] += ls;
        *(unsigned*)(Cp + (long)bz * sC + ((size_t)col << 12) + row0) =
            pk4e4(ev[0] * 0.0625f, ev[1] * 0.0625f, ev[2] * 0.0625f, ev[3] * 0.0625f);
      }
    }
#pragma unroll
    for (int n = 0; n < 4; ++n) {
      cs[n] += __shfl_xor(cs[n], 16);
      cs[n] += __shfl_xor(cs[n], 32);
    }
    if (lane < 16) {
#pragma unroll
      for (int n = 0; n < 4; ++n) {
        const int col = n0 + waveN * 64 + n * 16 + lane;
        atomicAdd(sums + ((size_t)bz << 10) + col, cs[n]);
      }
    }
  }
}

// ---------------------------------------------------------------------------
// fp8 GEMM, 128x256 tile, C = A @ Bt^T (e4m3 operands, BK=128, fp32 acc).
// K is PER-SLICE k-length; ldk is the row stride.
// OUTMODE 2: fp16 split-K partial (slice zt)
//         5: fp32 acc/(256*sums[row]) + bias[col]
// ---------------------------------------------------------------------------
template <int OUTMODE>
__global__ __launch_bounds__(512, 4) void gemm8(
    const unsigned char* __restrict__ A, const unsigned char* __restrict__ Bt,
    void* __restrict__ Cv, const float* __restrict__ bias,
    const float* __restrict__ sums,
    int N, int K, int ldk, int gx, int gy, int nsplit,
    long sA, long sB, long sC)
{
  __shared__ alignas(16) unsigned char smem[49152];
  const int tid  = threadIdx.x;
  const int lane = tid & 63;
  const int wave = tid >> 6;
  const int waveM = wave >> 2;
  const int waveN = wave & 3;

  const int nwg = (int)gridDim.x;
  const int cpx = nwg >> 3;
  const int wg  = (int)blockIdx.x;
  const int w   = (wg & 7) * cpx + (wg >> 3);
  const int x   = w % gx;
  const int rem = w / gx;
  const int y   = rem % gy;
  const int zt  = rem / gy;
  const int bz  = zt / nsplit;
  const int sp  = zt % nsplit;

  const int m0 = y * 128, n0 = x * 256;
  const size_t ldkB = (size_t)ldk;
  const size_t ldkB64 = ldkB * 64, ldkB128 = ldkB * 128;

  const int srow = tid >> 3;
  const int scol = ((tid * 16) & 127) ^ ((srow & 7) << 4);
  const char* ApR;
  const char* BpR;
  {
    const char* Ab = (const char*)A + (long)bz * sA + (long)sp * K + (size_t)m0 * ldkB;
    const char* Bb = (const char*)Bt + (long)bz * sB + (long)sp * K + (size_t)n0 * ldkB;
    ApR = Ab + (size_t)srow * ldkB + scol;
    BpR = Bb + (size_t)srow * ldkB + scol;
  }
  const unsigned oA0 = (unsigned)tid * 16;

  int offA[4], offB[4];
  {
    const int q16 = (lane >> 4) << 4;
#pragma unroll
    for (int mi = 0; mi < 4; ++mi) {
      const int r = waveM * 64 + mi * 16 + (lane & 15);
      offA[mi] = r * 128 + (q16 ^ ((r & 7) << 4));
    }
#pragma unroll
    for (int ni = 0; ni < 4; ++ni) {
      const int r = waveN * 64 + ni * 16 + (lane & 15);
      offB[ni] = 16384 + r * 128 + (q16 ^ ((r & 7) << 4));
    }
  }

  f32x4 acc[4][4] = {};

  const int nk = K >> 7;
  for (int kt = 0; kt < nk; ++kt) {
    const size_t kb = (size_t)kt * 128;
    gload_lds16(ApR + kb,                     smem + oA0);
    gload_lds16(ApR + ldkB64 + kb,            smem + oA0 + 8192);
    gload_lds16(BpR + kb,                     smem + 16384 + oA0);
    gload_lds16(BpR + ldkB64 + kb,            smem + 16384 + oA0 + 8192);
    gload_lds16(BpR + ldkB128 + kb,           smem + 16384 + oA0 + 16384);
    gload_lds16(BpR + ldkB128 + ldkB64 + kb,  smem + 16384 + oA0 + 24576);
    __syncthreads();
#pragma unroll
    for (int kk = 0; kk < 2; ++kk) {
      const int kx = kk << 6;
      lx2 aF[4], bF[4];
#pragma unroll
      for (int mi = 0; mi < 4; ++mi) aF[mi] = *(const lx2*)&smem[offA[mi] ^ kx];
#pragma unroll
      for (int ni = 0; ni < 4; ++ni) bF[ni] = *(const lx2*)&smem[offB[ni] ^ kx];
#pragma unroll
      for (int h = 0; h < 2; ++h)
#pragma unroll
        for (int mi = 0; mi < 4; ++mi)
#pragma unroll
          for (int ni = 0; ni < 4; ++ni)
            acc[mi][ni] = __builtin_amdgcn_mfma_f32_16x16x32_fp8_fp8(
                aF[mi][h], bF[ni][h], acc[mi][ni], 0, 0, 0);
    }
    __syncthreads();
  }

  const int rb = (lane >> 4) * 4;
  const int cb_ = lane & 15;
  const long zout = (OUTMODE == 2) ? (long)zt : (long)bz;
#pragma unroll
  for (int m = 0; m < 4; ++m) {
    const int row0 = m0 + waveM * 64 + m * 16 + rb;
    float i0 = 0, i1 = 0, i2 = 0, i3 = 0;
    if (OUTMODE == 5) {
      const float4 s4 = *(const float4*)&sums[(size_t)zout * 4096 + row0];
      i0 = 1.0f / (256.0f * s4.x); i1 = 1.0f / (256.0f * s4.y);
      i2 = 1.0f / (256.0f * s4.z); i3 = 1.0f / (256.0f * s4.w);
    }
#pragma unroll
    for (int n = 0; n < 4; ++n) {
      const int col = n0 + waveN * 64 + n * 16 + cb_;
      if (OUTMODE == 2) {
#pragma unroll
        for (int r = 0; r < 4; ++r)
          ((unsigned short*)Cv)[zout * sC + (size_t)(row0 + r) * N + col] = f2h(acc[m][n][r]);
      } else {
        const float badd = bias[col];
        float* C32 = (float*)Cv;
        C32[zout * sC + (size_t)(row0 + 0) * N + col] = acc[m][n][0] * i0 + badd;
        C32[zout * sC + (size_t)(row0 + 1) * N + col] = acc[m][n][1] * i1 + badd;
        C32[zout * sC + (size_t)(row0 + 2) * N + col] = acc[m][n][2] * i2 + badd;
        C32[zout * sC + (size_t)(row0 + 3) * N + col] = acc[m][n][3] * i3 + badd;
      }
    }
  }
}

// ---------------------------------------------------------------------------
// Weight transpose -> fp8 x8 (4 weights, z selects): WT8[z][c][r] = f8(8*W[r][c])
// ---------------------------------------------------------------------------
__global__ __launch_bounds__(256) void w_tr8(
    const float* __restrict__ W0, const float* __restrict__ W1,
    const float* __restrict__ W2, const float* __restrict__ W3,
    unsigned char* __restrict__ WT8b)
{
  __shared__ float tile[64][65];
  const int z = blockIdx.z;
  const float* W = (z == 0) ? W0 : (z == 1) ? W1 : (z == 2) ? W2 : W3;
  unsigned char* WT8 = WT8b + ((size_t)z << 20);
  const int c0 = blockIdx.x * 64;
  const int r0 = blockIdx.y * 64;
  const int tid = threadIdx.x;
  const int r = tid >> 2;
  const int cq = (tid & 3) * 16;
#pragma unroll
  for (int i = 0; i < 4; ++i) {
    const int c = cq + i * 4;
    const float4 v = *(const float4*)&W[(size_t)(r0 + r) * 1024 + c0 + c];
    tile[r][c + 0] = v.x;
    tile[r][c + 1] = v.y;
    tile[r][c + 2] = v.z;
    tile[r][c + 3] = v.w;
  }
  __syncthreads();
  const int c = tid >> 2;
  const int rq = (tid & 3) * 16;
  unsigned u4[4];
#pragma unroll
  for (int j = 0; j < 4; ++j)
    u4[j] = pk4e4(tile[rq + 4 * j + 0][c] * 8.f, tile[rq + 4 * j + 1][c] * 8.f,
                  tile[rq + 4 * j + 2][c] * 8.f, tile[rq + 4 * j + 3][c] * 8.f);
  *(uint4*)(WT8 + (size_t)(c0 + c) * 1024 + r0 + rq) = *(const uint4*)u4;
}

// ---------------------------------------------------------------------------
// split-K x4 reduce of fp16 partials -> fp8 M with normalization:
// M8[b][dk][dv] = f8( sum * 2^22 / (skr[b][dk] * svr[b][dv]) )
// ---------------------------------------------------------------------------
__global__ __launch_bounds__(256) void red4m(
    const unsigned short* __restrict__ P, const float* __restrict__ skr,
    const float* __restrict__ svr, unsigned char* __restrict__ O)
{
  const int i = blockIdx.x * 256 + threadIdx.x;
  const int b = i >> 18;
  const int j = i & 262143;
  const int dk = j >> 8;
  const int dv0 = (j & 255) << 2;
  float s0 = 0, s1 = 0, s2 = 0, s3 = 0;
#pragma unroll
  for (int sl = 0; sl < 4; ++sl) {
    const uint2 u = *(const uint2*)(P + (((long)(b * 4 + sl)) << 20) + ((long)j << 2));
    s0 += h2f(u.x & 0xffff); s1 += h2f(u.x >> 16);
    s2 += h2f(u.y & 0xffff); s3 += h2f(u.y >> 16);
  }
  const float fk = 4194304.0f / skr[(b << 10) + dk];
  const float4 fv = *(const float4*)&svr[(b << 10) + dv0];
  ((unsigned*)O)[i] = pk4e4(s0 * fk / fv.x, s1 * fk / fv.y,
                            s2 * fk / fv.z, s3 * fk / fv.w);
}

// ---------------------------------------------------------------------------
// split-K x4 reduce -> fp8 GT: GT8[b][i] = f8( sum / 32 )
// ---------------------------------------------------------------------------
__global__ __launch_bounds__(256) void red4g(
    const unsigned short* __restrict__ P, unsigned char* __restrict__ O)
{
  const int i = blockIdx.x * 256 + threadIdx.x;
  const int b = i >> 18;
  const int j = i & 262143;
  float s0 = 0, s1 = 0, s2 = 0, s3 = 0;
#pragma unroll
  for (int sl = 0; sl < 4; ++sl) {
    const uint2 u = *(const uint2*)(P + (((long)(b * 4 + sl)) << 20) + ((long)j << 2));
    s0 += h2f(u.x & 0xffff); s1 += h2f(u.x >> 16);
    s2 += h2f(u.y & 0xffff); s3 += h2f(u.y >> 16);
  }
  ((unsigned*)O)[i] = pk4e4(s0 * 0.03125f, s1 * 0.03125f,
                            s2 * 0.03125f, s3 * 0.03125f);
}

// ---------------------------------------------------------------------------
extern "C" void kernel_launch(void* const* d_in, const int* in_sizes, int n_in,
                              void* d_out, int out_size, void* d_ws, size_t ws_size,
                              hipStream_t stream) {
  const float* q  = (const float*)d_in[0];
  const float* k  = (const float*)d_in[1];
  const float* v  = (const float*)d_in[2];
  const float* Wq = (const float*)d_in[3];
  const float* bq = (const float*)d_in[4];
  const float* Wk = (const float*)d_in[5];
  const float* bk = (const float*)d_in[6];
  const float* Wv = (const float*)d_in[7];
  const float* bv = (const float*)d_in[8];
  const float* Wo = (const float*)d_in[9];
  const float* bo = (const float*)d_in[10];
  float* out = (float*)d_out;

  // workspace (~143 MB)
  char* p = (char*)d_ws;
  unsigned short* Part = (unsigned short*)p; p += 33554432;   // fp16 [16][2^20]
  unsigned char* WT8b = (unsigned char*)p;   p += 4194304;    // 4x fp8 [1024][1024], x8
  unsigned char* Xq8  = (unsigned char*)p;   p += 16777216;   // fp8 [4][4096][1024]
  unsigned char* Xk8  = (unsigned char*)p;   p += 16777216;
  unsigned char* Xv8  = (unsigned char*)p;   p += 16777216;
  unsigned char* Eq8  = (unsigned char*)p;   p += 16777216;   // fp8 [4][4096][1024]
  unsigned char* ETk8 = (unsigned char*)p;   p += 16777216;   // fp8 [4][1024][4096]
  unsigned char* ETv8 = (unsigned char*)p;   p += 16777216;
  unsigned char* Mh8  = (unsigned char*)p;   p += 4194304;    // fp8 [4][1024][1024]
  unsigned char* GT8  = (unsigned char*)p;   p += 4194304;    // fp8 [4][1024][1024]
  float* sqraw = (float*)p; p += 16384 * 4;   // raw row-sums of Eq
  float* skraw = (float*)p; p += 4096 * 4;    // raw col-sums of Ek
  float* svraw = (float*)p; p += 4096 * 4;    // raw col-sums of Ev

  const dim3 blk(256);
  const dim3 blk512(512);
  const long S22 = 4096L * 1024;
  const long S20 = 1024L * 1024;

  // zero the atomic sum accumulators (96 KB; graph-capturable)
  hipMemsetAsync(sqraw, 0, (16384 + 4096 + 4096) * sizeof(float), stream);

  // weights -> fp8 x8 transposed (one launch)
  w_tr8<<<dim3(16, 16, 4), blk, 0, stream>>>(Wq, Wk, Wv, Wo, WT8b);

  // q,k,v fp32 -> fp8 (streaming; 192 MB read + 48 MB write)
  conv3<<<dim3(8192, 3), blk, 0, stream>>>(q, k, v, Xq8, Xk8, Xv8);

  // ---- merged fp8 projections (pure gload_lds core): Eq8/ETk8/ETv8 + sums
  proj3<<<1536, blk512, 0, stream>>>(Xq8, Xk8, Xv8, WT8b, bq, bk, bv,
                                     Eq8, ETk8, ETv8, sqraw, skraw, svraw);

  // ---- M partials (fp8 GEMM, K=4096 split x4, per-slice K=1024):
  //      Mh8 = f8(red4(P) * 2^22 / (sk*sv))  (= M_true * 2^14)
  gemm8<2><<<512, blk512, 0, stream>>>(ETk8, ETv8, Part, nullptr, nullptr,
      1024, 1024, 4096, 4, 8, 4, S22, S22, S20);
  red4m<<<4096, blk, 0, stream>>>(Part, skraw, svraw, Mh8);

  // ---- GTraw (fp8 GEMM, K=1024 split x4, per-slice K=256):
  //      GT8 = f8(red4(P)/32)  (= G^T * 2^12)
  gemm8<2><<<512, blk512, 0, stream>>>(WT8b + (3L << 20), Mh8, Part, nullptr, nullptr,
      1024, 256, 1024, 4, 8, 4, 0, S20, S20);
  red4g<<<4096, blk, 0, stream>>>(Part, GT8);

  // ---- Out (fp8 GEMM): Out = (Eq8 @ GT8^T)/(256*sq) + bo
  gemm8<5><<<512, blk512, 0, stream>>>(Eq8, GT8, out, bo, sqraw,
      1024, 1024, 1024, 4, 32, 1, S22, S20, S22);

  (void)in_sizes; (void)n_in; (void)out_size; (void)ws_size;
}